// Round 16
// baseline (130.911 us; speedup 1.0000x reference)
//
#include <hip/hip_runtime.h>
#include <hip/hip_bf16.h>

typedef __attribute__((ext_vector_type(8))) short short8;
typedef __attribute__((ext_vector_type(4))) float f32x4;

#define B_ 2
#define S_ 512
#define D_ 768
#define NH 12
#define HD 64

__device__ __forceinline__ short f2bf(float f) {
    union { __hip_bfloat16 h; short s; } u;
    u.h = __float2bfloat16(f);
    return u.s;
}

__device__ __forceinline__ float bf2f(short s) {
    union { unsigned u; float f; } v;
    v.u = ((unsigned)(unsigned short)s) << 16;
    return v.f;
}

__device__ __forceinline__ f32x4 ntload4(const float* p) {
    return __builtin_nontemporal_load((const f32x4*)p);
}

// ---------------------------------------------------------------------------
// Shared GEMM body: C = hidden-tile . W-tile^T + bias for one (mt, nt).
// mat: 0=q (scaled, (b,n,s,h)) 1=k ((b,n,s,h)) 2=v (bf16 transposed (b,n,h,s)).
// Must be called with all 256 threads.
// ---------------------------------------------------------------------------
__device__ __forceinline__ void proj_body(
    const float* __restrict__ hidden, const float* __restrict__ W,
    const float* __restrict__ bias, int mt, int nt, int mat,
    short* __restrict__ dst, short* hs, short* wt)
{
    const int m0 = mt * 64, n0 = nt * 64;
    const int tid = threadIdx.x;
    const int w = tid >> 6, l = tid & 63;
    const int sr = tid >> 2, sc = (tid & 3) * 16;

    f32x4 acc[4];
    #pragma unroll
    for (int i = 0; i < 4; ++i) acc[i] = (f32x4){0.f, 0.f, 0.f, 0.f};

    const int arow = (w * 16 + (l & 15)) * 72 + (l >> 4) * 8;

    for (int kt = 0; kt < 12; ++kt) {
        const int d0 = kt * 64;
        if (kt) __syncthreads();
        {
            const float4* sa = (const float4*)(hidden + (size_t)(m0 + sr) * D_ + d0 + sc);
            float4 x0 = sa[0], x1 = sa[1], x2 = sa[2], x3 = sa[3];
            short8 p0 = {f2bf(x0.x), f2bf(x0.y), f2bf(x0.z), f2bf(x0.w),
                         f2bf(x1.x), f2bf(x1.y), f2bf(x1.z), f2bf(x1.w)};
            short8 p1 = {f2bf(x2.x), f2bf(x2.y), f2bf(x2.z), f2bf(x2.w),
                         f2bf(x3.x), f2bf(x3.y), f2bf(x3.z), f2bf(x3.w)};
            *(short8*)&hs[sr * 72 + sc]     = p0;
            *(short8*)&hs[sr * 72 + sc + 8] = p1;
            const float4* sb = (const float4*)(W + (size_t)(n0 + sr) * D_ + d0 + sc);
            float4 y0 = sb[0], y1 = sb[1], y2 = sb[2], y3 = sb[3];
            short8 q0 = {f2bf(y0.x), f2bf(y0.y), f2bf(y0.z), f2bf(y0.w),
                         f2bf(y1.x), f2bf(y1.y), f2bf(y1.z), f2bf(y1.w)};
            short8 q1 = {f2bf(y2.x), f2bf(y2.y), f2bf(y2.z), f2bf(y2.w),
                         f2bf(y3.x), f2bf(y3.y), f2bf(y3.z), f2bf(y3.w)};
            *(short8*)&wt[sr * 72 + sc]     = q0;
            *(short8*)&wt[sr * 72 + sc + 8] = q1;
        }
        __syncthreads();
        short8 a0 = *(const short8*)&hs[arow];
        short8 a1 = *(const short8*)&hs[arow + 32];
        #pragma unroll
        for (int ct = 0; ct < 4; ++ct) {
            const int brow = (ct * 16 + (l & 15)) * 72 + (l >> 4) * 8;
            short8 b0 = *(const short8*)&wt[brow];
            short8 b1 = *(const short8*)&wt[brow + 32];
            acc[ct] = __builtin_amdgcn_mfma_f32_16x16x32_bf16(a0, b0, acc[ct], 0, 0, 0);
            acc[ct] = __builtin_amdgcn_mfma_f32_16x16x32_bf16(a1, b1, acc[ct], 0, 0, 0);
        }
    }

    if (mat == 2) {
        __syncthreads();
        #pragma unroll
        for (int ct = 0; ct < 4; ++ct) {
            #pragma unroll
            for (int rr = 0; rr < 4; ++rr) {
                const int m_l = w * 16 + (l >> 4) * 4 + rr;
                const int n_l = ct * 16 + (l & 15);
                hs[n_l * 68 + m_l] = f2bf(acc[ct][rr] + bias[n0 + n_l]);
            }
        }
        __syncthreads();
        const int b   = m0 >> 9;
        const int s0b = m0 & 511;
        #pragma unroll
        for (int j = 0; j < 2; ++j) {
            const int idx  = j * 256 + tid;
            const int h    = idx >> 3;
            const int sseg = (idx & 7) * 8;
            short8 vv = *(const short8*)&hs[h * 68 + sseg];
            *(short8*)(dst + ((size_t)(b * NH + nt) * HD + h) * S_ + s0b + sseg) = vv;
        }
    } else {
        const float sca = (mat == 0) ? 0.125f : 1.0f;
        #pragma unroll
        for (int ct = 0; ct < 4; ++ct) {
            #pragma unroll
            for (int rr = 0; rr < 4; ++rr) {
                const int m_l = w * 16 + (l >> 4) * 4 + rr;
                const int n_l = ct * 16 + (l & 15);
                const int m = m0 + m_l;
                const int b = m >> 9, s = m & 511;
                float v = (acc[ct][rr] + bias[n0 + n_l]) * sca;
                dst[(((size_t)(b * NH + nt) * S_) + s) * HD + n_l] = f2bf(v);
            }
        }
    }
}

// ---------------------------------------------------------------------------
// Kernel 1: q projection only (192 blocks) — the only serial prerequisite
// of the rel stream.
// ---------------------------------------------------------------------------
__global__ __launch_bounds__(256) void qproj(
    const float* __restrict__ hidden, const float* __restrict__ Wq,
    const float* __restrict__ bq, short* __restrict__ qbf)
{
    __shared__ short hs[64 * 72];
    __shared__ short wt[64 * 72];
    proj_body(hidden, Wq, bq, blockIdx.x, blockIdx.y, 0, qbf, hs, wt);
}

// ---------------------------------------------------------------------------
// Kernel 2 (FAT): K/V projection ∥ rel stream.
//  - blocks [0, 384): K and V projections — dispatched FIRST so their long
//    (~25 µs) barrier-synced GEMMs run during the stream's beginning and
//    finish well inside it (R15 had them last -> they extended the kernel).
//  - blocks [384, 8576): rel path. One 16-k subtile per wave, NT loads,
//    fire-and-exit (sustains the ~4.7 TB/s demand clamp). Pure store of
//    bf16 rel scores to relsc (b,s,n,k).
// ---------------------------------------------------------------------------
__global__ __launch_bounds__(256) void relkv(
    const short* __restrict__ qbf,
    const float* __restrict__ rel1, const float* __restrict__ rel2, const float* __restrict__ rel3,
    const float* __restrict__ hidden,
    const float* __restrict__ Wk, const float* __restrict__ bk,
    const float* __restrict__ Wv, const float* __restrict__ bv,
    short* __restrict__ relsc, short* __restrict__ kbf, short* __restrict__ vbf)
{
    __shared__ short hs[64 * 72];
    __shared__ short wt[64 * 72];

    const int bid = blockIdx.x;
    const int tid = threadIdx.x;

    if (bid >= 384) {
        const int rb = bid - 384;
        const int w = tid >> 6, l = tid & 63;
        const int kt = rb & 7;
        const int s  = (rb >> 3) & 511;
        const int b  = rb >> 12;

        const int rowsel = l & 15;       // A: n-row / B: k-row / D: k-col
        const int hc     = (l >> 4) * 8; // h-chunk base

        const int kc = kt * 4 + w;       // k-subtile 0..31
        const size_t rbase = ((size_t)(b * S_ + s)) * S_ * HD;
        const size_t ro = rbase + (size_t)(kc * 16 + rowsel) * HD + hc;

        f32x4 p0a = ntload4(rel1 + ro);
        f32x4 p0b = ntload4(rel1 + ro + 4);
        f32x4 q0a = ntload4(rel1 + ro + 32);
        f32x4 q0b = ntload4(rel1 + ro + 36);
        f32x4 p1a = ntload4(rel2 + ro);
        f32x4 p1b = ntload4(rel2 + ro + 4);
        f32x4 q1a = ntload4(rel2 + ro + 32);
        f32x4 q1b = ntload4(rel2 + ro + 36);
        f32x4 p2a = ntload4(rel3 + ro);
        f32x4 p2b = ntload4(rel3 + ro + 4);
        f32x4 q2a = ntload4(rel3 + ro + 32);
        f32x4 q2b = ntload4(rel3 + ro + 36);

        short8 a0 = {0, 0, 0, 0, 0, 0, 0, 0};
        short8 a1 = {0, 0, 0, 0, 0, 0, 0, 0};
        if (rowsel < NH) {
            const short* qp = qbf + (((size_t)(b * NH + rowsel) * S_) + s) * HD;
            a0 = *(const short8*)(qp + hc);
            a1 = *(const short8*)(qp + hc + 32);
        }

        short8 b0 = {
            f2bf(p0a.x + p1a.x + p2a.x), f2bf(p0a.y + p1a.y + p2a.y),
            f2bf(p0a.z + p1a.z + p2a.z), f2bf(p0a.w + p1a.w + p2a.w),
            f2bf(p0b.x + p1b.x + p2b.x), f2bf(p0b.y + p1b.y + p2b.y),
            f2bf(p0b.z + p1b.z + p2b.z), f2bf(p0b.w + p1b.w + p2b.w)};
        short8 b1 = {
            f2bf(q0a.x + q1a.x + q2a.x), f2bf(q0a.y + q1a.y + q2a.y),
            f2bf(q0a.z + q1a.z + q2a.z), f2bf(q0a.w + q1a.w + q2a.w),
            f2bf(q0b.x + q1b.x + q2b.x), f2bf(q0b.y + q1b.y + q2b.y),
            f2bf(q0b.z + q1b.z + q2b.z), f2bf(q0b.w + q1b.w + q2b.w)};

        f32x4 acc = (f32x4){0.f, 0.f, 0.f, 0.f};
        acc = __builtin_amdgcn_mfma_f32_16x16x32_bf16(a0, b0, acc, 0, 0, 0);
        acc = __builtin_amdgcn_mfma_f32_16x16x32_bf16(a1, b1, acc, 0, 0, 0);

        const int kg = kc * 16 + rowsel;
        #pragma unroll
        for (int rr = 0; rr < 4; ++rr) {
            const int n = (l >> 4) * 4 + rr;
            if (n < NH)
                relsc[(((size_t)(b * S_ + s)) * NH + n) * S_ + kg] = f2bf(acc[rr]);
        }
    } else {
        const int j    = bid;                 // 0..383
        const int mt   = j & 15;
        const int rest = j >> 4;              // 0..23
        const int nt   = rest % 12;
        if (rest < 12) proj_body(hidden, Wk, bk, mt, nt, 1, kbf, hs, wt);
        else           proj_body(hidden, Wv, bv, mt, nt, 2, vbf, hs, wt);
    }
}

// ---------------------------------------------------------------------------
// Kernel 3: QK-MFMA + relsc/mask add + softmax + MFMA PV.
// Grid (st=32, n=12, b=2), 256 threads, LDS ~50 KB (3 blk/CU).
// ---------------------------------------------------------------------------
__global__ __launch_bounds__(256) void smqkpv(
    const short* __restrict__ qbf, const short* __restrict__ kbf,
    const short* __restrict__ relsc, const float* __restrict__ mask,
    const short* __restrict__ vbf, float* __restrict__ out)
{
    __shared__ float sc[16][520];
    __shared__ short pbf[16][524];

    const int st  = blockIdx.x;
    const int n   = blockIdx.y;
    const int b   = blockIdx.z;
    const int s0  = st * 16;
    const int tid = threadIdx.x;
    const int w = tid >> 6, l = tid & 63;

    // --- QK^T via MFMA: wave w owns k-range [w*128, w*128+128) ---
    const int arow = l & 15;
    const int g    = l >> 4;

    const short* qp = qbf + (((size_t)(b * NH + n) * S_) + s0 + arow) * HD + g * 8;
    short8 a0 = *(const short8*)(qp);
    short8 a1 = *(const short8*)(qp + 32);

    f32x4 acc[8];
    #pragma unroll
    for (int t = 0; t < 8; ++t) acc[t] = (f32x4){0.f, 0.f, 0.f, 0.f};

    #pragma unroll
    for (int t = 0; t < 8; ++t) {
        const int k0 = (w * 8 + t) * 16;
        const short* kp = kbf + (((size_t)(b * NH + n) * S_) + k0 + arow) * HD + g * 8;
        short8 b0 = *(const short8*)(kp);
        short8 b1 = *(const short8*)(kp + 32);
        acc[t] = __builtin_amdgcn_mfma_f32_16x16x32_bf16(a0, b0, acc[t], 0, 0, 0);
        acc[t] = __builtin_amdgcn_mfma_f32_16x16x32_bf16(a1, b1, acc[t], 0, 0, 0);
    }

    #pragma unroll
    for (int t = 0; t < 8; ++t) {
        const int k0 = (w * 8 + t) * 16;
        #pragma unroll
        for (int rr = 0; rr < 4; ++rr)
            sc[g * 4 + rr][k0 + arow] = acc[t][rr];
    }
    __syncthreads();

    // --- softmax with fused relsc + mask add (PB-Relax == plain softmax) ---
    for (int r = 0; r < 4; ++r) {
        const int row = w * 4 + r;
        const short* rp = relsc + (((size_t)(b * S_ + s0 + row)) * NH + n) * S_;
        float vals[8];
        float m = -1e30f;
        #pragma unroll
        for (int i = 0; i < 8; ++i) {
            vals[i] = sc[row][l + 64 * i] + bf2f(rp[l + 64 * i]) + mask[b * S_ + l + 64 * i];
            m = fmaxf(m, vals[i]);
        }
        #pragma unroll
        for (int off = 32; off >= 1; off >>= 1) m = fmaxf(m, __shfl_xor(m, off));
        float sum = 0.f;
        #pragma unroll
        for (int i = 0; i < 8; ++i) { vals[i] = __expf(vals[i] - m); sum += vals[i]; }
        #pragma unroll
        for (int off = 32; off >= 1; off >>= 1) sum += __shfl_xor(sum, off);
        const float inv = 1.0f / sum;
        #pragma unroll
        for (int i = 0; i < 8; ++i) pbf[row][l + 64 * i] = f2bf(vals[i] * inv);
    }
    __syncthreads();

    // --- PV via MFMA: out[s][h] = sum_k P[s][k] V^T[h][k] ---
    f32x4 pacc = (f32x4){0.f, 0.f, 0.f, 0.f};
    const short* vrow = vbf + ((size_t)(b * NH + n) * HD + w * 16 + arow) * S_ + g * 8;
    #pragma unroll
    for (int kk = 0; kk < 16; ++kk) {
        short8 aP = *(const short8*)&pbf[arow][kk * 32 + g * 8];
        short8 bV = *(const short8*)(vrow + kk * 32);
        pacc = __builtin_amdgcn_mfma_f32_16x16x32_bf16(aP, bV, pacc, 0, 0, 0);
    }
    #pragma unroll
    for (int rr = 0; rr < 4; ++rr) {
        const int srow = g * 4 + rr;
        out[((size_t)(b * S_ + s0 + srow)) * D_ + n * HD + w * 16 + arow] = pacc[rr];
    }
}

extern "C" void kernel_launch(void* const* d_in, const int* in_sizes, int n_in,
                              void* d_out, int out_size, void* d_ws, size_t ws_size,
                              hipStream_t stream) {
    const float* hidden = (const float*)d_in[0];
    const float* mask   = (const float*)d_in[1];
    const float* rel1   = (const float*)d_in[2];
    const float* rel2   = (const float*)d_in[3];
    const float* rel3   = (const float*)d_in[4];
    const float* Wq     = (const float*)d_in[5];
    const float* bq     = (const float*)d_in[6];
    const float* Wk     = (const float*)d_in[7];
    const float* bk     = (const float*)d_in[8];
    const float* Wv     = (const float*)d_in[9];
    const float* bv     = (const float*)d_in[10];
    float* out = (float*)d_out;

    const size_t per = (size_t)B_ * NH * S_ * HD;        // 786432
    short* qbf   = (short*)d_ws;                          // 1.5 MB
    short* kbf   = qbf + per;                             // 1.5 MB
    short* vbf   = kbf + per;                             // 1.5 MB (b,n,h,s)
    short* relsc = vbf + per;                             // 12.6 MB bf16 (b,s,n,k)

    qproj<<<dim3(16, 12), 256, 0, stream>>>(hidden, Wq, bq, qbf);
    relkv<<<dim3(384 + 8192), 256, 0, stream>>>(qbf, rel1, rel2, rel3,
                                                hidden, Wk, bk, Wv, bv,
                                                relsc, kbf, vbf);
    smqkpv<<<dim3(S_ / 16, NH, B_), 256, 0, stream>>>(qbf, kbf, relsc, mask, vbf, out);
}

// Round 17
// 126.788 us; speedup vs baseline: 1.0325x; 1.0325x over previous
//
#include <hip/hip_runtime.h>
#include <hip/hip_bf16.h>

typedef __attribute__((ext_vector_type(8))) short short8;
typedef __attribute__((ext_vector_type(4))) float f32x4;

#define B_ 2
#define S_ 512
#define D_ 768
#define NH 12
#define HD 64

__device__ __forceinline__ short f2bf(float f) {
    union { __hip_bfloat16 h; short s; } u;
    u.h = __float2bfloat16(f);
    return u.s;
}

__device__ __forceinline__ float bf2f(short s) {
    union { unsigned u; float f; } v;
    v.u = ((unsigned)(unsigned short)s) << 16;
    return v.f;
}

__device__ __forceinline__ f32x4 ntload4(const float* p) {
    return __builtin_nontemporal_load((const f32x4*)p);
}

// ---------------------------------------------------------------------------
// Kernel 1: QKV projection, bf16 MFMA, fp32 accumulate.
// q -> qbf (bf16, scaled 1/8) (b,n,s,h); k -> kbf (bf16) (b,n,s,h);
// v -> vbf (bf16, TRANSPOSED) (b,n,h,s) via LDS transpose.
// ---------------------------------------------------------------------------
__global__ __launch_bounds__(256) void qkv_gemm(
    const float* __restrict__ hidden,
    const float* __restrict__ Wq, const float* __restrict__ Wk, const float* __restrict__ Wv,
    const float* __restrict__ bq, const float* __restrict__ bk, const float* __restrict__ bv,
    short* __restrict__ qbf, short* __restrict__ kbf, short* __restrict__ vbf)
{
    __shared__ short hs[64 * 72];
    __shared__ short wt[64 * 72];

    const int mt = blockIdx.x, nt = blockIdx.y, mat = blockIdx.z;
    const int m0 = mt * 64, n0 = nt * 64;
    const float* W    = (mat == 0) ? Wq : ((mat == 1) ? Wk : Wv);
    const float* bias = (mat == 0) ? bq : ((mat == 1) ? bk : bv);

    const int tid = threadIdx.x;
    const int w = tid >> 6, l = tid & 63;
    const int sr = tid >> 2, sc = (tid & 3) * 16;

    f32x4 acc[4];
    #pragma unroll
    for (int i = 0; i < 4; ++i) acc[i] = (f32x4){0.f, 0.f, 0.f, 0.f};

    const int arow = (w * 16 + (l & 15)) * 72 + (l >> 4) * 8;

    for (int kt = 0; kt < 12; ++kt) {
        const int d0 = kt * 64;
        if (kt) __syncthreads();
        {
            const float4* sa = (const float4*)(hidden + (size_t)(m0 + sr) * D_ + d0 + sc);
            float4 x0 = sa[0], x1 = sa[1], x2 = sa[2], x3 = sa[3];
            short8 p0 = {f2bf(x0.x), f2bf(x0.y), f2bf(x0.z), f2bf(x0.w),
                         f2bf(x1.x), f2bf(x1.y), f2bf(x1.z), f2bf(x1.w)};
            short8 p1 = {f2bf(x2.x), f2bf(x2.y), f2bf(x2.z), f2bf(x2.w),
                         f2bf(x3.x), f2bf(x3.y), f2bf(x3.z), f2bf(x3.w)};
            *(short8*)&hs[sr * 72 + sc]     = p0;
            *(short8*)&hs[sr * 72 + sc + 8] = p1;
            const float4* sb = (const float4*)(W + (size_t)(n0 + sr) * D_ + d0 + sc);
            float4 y0 = sb[0], y1 = sb[1], y2 = sb[2], y3 = sb[3];
            short8 q0 = {f2bf(y0.x), f2bf(y0.y), f2bf(y0.z), f2bf(y0.w),
                         f2bf(y1.x), f2bf(y1.y), f2bf(y1.z), f2bf(y1.w)};
            short8 q1 = {f2bf(y2.x), f2bf(y2.y), f2bf(y2.z), f2bf(y2.w),
                         f2bf(y3.x), f2bf(y3.y), f2bf(y3.z), f2bf(y3.w)};
            *(short8*)&wt[sr * 72 + sc]     = q0;
            *(short8*)&wt[sr * 72 + sc + 8] = q1;
        }
        __syncthreads();
        short8 a0 = *(const short8*)&hs[arow];
        short8 a1 = *(const short8*)&hs[arow + 32];
        #pragma unroll
        for (int ct = 0; ct < 4; ++ct) {
            const int brow = (ct * 16 + (l & 15)) * 72 + (l >> 4) * 8;
            short8 b0 = *(const short8*)&wt[brow];
            short8 b1 = *(const short8*)&wt[brow + 32];
            acc[ct] = __builtin_amdgcn_mfma_f32_16x16x32_bf16(a0, b0, acc[ct], 0, 0, 0);
            acc[ct] = __builtin_amdgcn_mfma_f32_16x16x32_bf16(a1, b1, acc[ct], 0, 0, 0);
        }
    }

    if (mat == 2) {
        __syncthreads();
        #pragma unroll
        for (int ct = 0; ct < 4; ++ct) {
            #pragma unroll
            for (int rr = 0; rr < 4; ++rr) {
                const int m_l = w * 16 + (l >> 4) * 4 + rr;
                const int n_l = ct * 16 + (l & 15);
                hs[n_l * 68 + m_l] = f2bf(acc[ct][rr] + bias[n0 + n_l]);
            }
        }
        __syncthreads();
        const int b   = m0 >> 9;
        const int s0b = m0 & 511;
        #pragma unroll
        for (int j = 0; j < 2; ++j) {
            const int idx  = j * 256 + tid;
            const int h    = idx >> 3;
            const int sseg = (idx & 7) * 8;
            short8 vv = *(const short8*)&hs[h * 68 + sseg];
            *(short8*)(vbf + ((size_t)(b * NH + nt) * HD + h) * S_ + s0b + sseg) = vv;
        }
    } else {
        const float sca = (mat == 0) ? 0.125f : 1.0f;
        #pragma unroll
        for (int ct = 0; ct < 4; ++ct) {
            #pragma unroll
            for (int rr = 0; rr < 4; ++rr) {
                const int m_l = w * 16 + (l >> 4) * 4 + rr;
                const int n_l = ct * 16 + (l & 15);
                const int m = m0 + m_l;
                const int b = m >> 9, s = m & 511;
                float v = (acc[ct][rr] + bias[n0 + n_l]) * sca;
                const size_t dst = (((size_t)(b * NH + nt) * S_) + s) * HD + n_l;
                if (mat == 0) qbf[dst] = f2bf(v);
                else          kbf[dst] = f2bf(v);
            }
        }
    }
}

// ---------------------------------------------------------------------------
// Kernel 2: rel stream — PURE (no guests). One 16-k subtile per wave, NT
// loads, fire-and-exit (sustains the ~4.7 TB/s demand clamp). bf16 store
// to relsc (b,s,n,k). Grid (kt=8, s=512, b=2), 256 threads.
// ---------------------------------------------------------------------------
__global__ __launch_bounds__(256) void score_rel(
    const short* __restrict__ qbf,
    const float* __restrict__ rel1, const float* __restrict__ rel2, const float* __restrict__ rel3,
    short* __restrict__ relsc)
{
    const int kt = blockIdx.x;
    const int s  = blockIdx.y;
    const int b  = blockIdx.z;
    const int tid = threadIdx.x;
    const int w = tid >> 6, l = tid & 63;

    const int rowsel = l & 15;       // A: n-row / B: k-row / D: k-col
    const int hc     = (l >> 4) * 8; // h-chunk base

    const int kc = kt * 4 + w;       // k-subtile 0..31
    const size_t rbase = ((size_t)(b * S_ + s)) * S_ * HD;
    const size_t ro = rbase + (size_t)(kc * 16 + rowsel) * HD + hc;

    f32x4 p0a = ntload4(rel1 + ro);
    f32x4 p0b = ntload4(rel1 + ro + 4);
    f32x4 q0a = ntload4(rel1 + ro + 32);
    f32x4 q0b = ntload4(rel1 + ro + 36);
    f32x4 p1a = ntload4(rel2 + ro);
    f32x4 p1b = ntload4(rel2 + ro + 4);
    f32x4 q1a = ntload4(rel2 + ro + 32);
    f32x4 q1b = ntload4(rel2 + ro + 36);
    f32x4 p2a = ntload4(rel3 + ro);
    f32x4 p2b = ntload4(rel3 + ro + 4);
    f32x4 q2a = ntload4(rel3 + ro + 32);
    f32x4 q2b = ntload4(rel3 + ro + 36);

    short8 a0 = {0, 0, 0, 0, 0, 0, 0, 0};
    short8 a1 = {0, 0, 0, 0, 0, 0, 0, 0};
    if (rowsel < NH) {
        const short* qp = qbf + (((size_t)(b * NH + rowsel) * S_) + s) * HD;
        a0 = *(const short8*)(qp + hc);
        a1 = *(const short8*)(qp + hc + 32);
    }

    short8 b0 = {
        f2bf(p0a.x + p1a.x + p2a.x), f2bf(p0a.y + p1a.y + p2a.y),
        f2bf(p0a.z + p1a.z + p2a.z), f2bf(p0a.w + p1a.w + p2a.w),
        f2bf(p0b.x + p1b.x + p2b.x), f2bf(p0b.y + p1b.y + p2b.y),
        f2bf(p0b.z + p1b.z + p2b.z), f2bf(p0b.w + p1b.w + p2b.w)};
    short8 b1 = {
        f2bf(q0a.x + q1a.x + q2a.x), f2bf(q0a.y + q1a.y + q2a.y),
        f2bf(q0a.z + q1a.z + q2a.z), f2bf(q0a.w + q1a.w + q2a.w),
        f2bf(q0b.x + q1b.x + q2b.x), f2bf(q0b.y + q1b.y + q2b.y),
        f2bf(q0b.z + q1b.z + q2b.z), f2bf(q0b.w + q1b.w + q2b.w)};

    f32x4 acc = (f32x4){0.f, 0.f, 0.f, 0.f};
    acc = __builtin_amdgcn_mfma_f32_16x16x32_bf16(a0, b0, acc, 0, 0, 0);
    acc = __builtin_amdgcn_mfma_f32_16x16x32_bf16(a1, b1, acc, 0, 0, 0);

    const int kg = kc * 16 + rowsel;
    #pragma unroll
    for (int rr = 0; rr < 4; ++rr) {
        const int n = (l >> 4) * 4 + rr;
        if (n < NH)
            relsc[(((size_t)(b * S_ + s)) * NH + n) * S_ + kg] = f2bf(acc[rr]);
    }
}

// ---------------------------------------------------------------------------
// Kernel 3: QK-MFMA + relsc/mask add + softmax + MFMA PV.
// LDS: bf16 QK scores (16.6 KB) + bf16 probs (16.8 KB) = 33.4 KB -> 4 blk/CU.
// Grid (st=32, n=12, b=2), 256 threads.
// ---------------------------------------------------------------------------
__global__ __launch_bounds__(256) void smqkpv(
    const short* __restrict__ qbf, const short* __restrict__ kbf,
    const short* __restrict__ relsc, const float* __restrict__ mask,
    const short* __restrict__ vbf, float* __restrict__ out)
{
    __shared__ short scb[16][520];   // bf16 QK scores
    __shared__ short pbf[16][524];   // bf16 probs

    const int st  = blockIdx.x;
    const int n   = blockIdx.y;
    const int b   = blockIdx.z;
    const int s0  = st * 16;
    const int tid = threadIdx.x;
    const int w = tid >> 6, l = tid & 63;

    // --- QK^T via MFMA: wave w owns k-range [w*128, w*128+128) ---
    const int arow = l & 15;
    const int g    = l >> 4;

    const short* qp = qbf + (((size_t)(b * NH + n) * S_) + s0 + arow) * HD + g * 8;
    short8 a0 = *(const short8*)(qp);
    short8 a1 = *(const short8*)(qp + 32);

    f32x4 acc[8];
    #pragma unroll
    for (int t = 0; t < 8; ++t) acc[t] = (f32x4){0.f, 0.f, 0.f, 0.f};

    #pragma unroll
    for (int t = 0; t < 8; ++t) {
        const int k0 = (w * 8 + t) * 16;
        const short* kp = kbf + (((size_t)(b * NH + n) * S_) + k0 + arow) * HD + g * 8;
        short8 b0 = *(const short8*)(kp);
        short8 b1 = *(const short8*)(kp + 32);
        acc[t] = __builtin_amdgcn_mfma_f32_16x16x32_bf16(a0, b0, acc[t], 0, 0, 0);
        acc[t] = __builtin_amdgcn_mfma_f32_16x16x32_bf16(a1, b1, acc[t], 0, 0, 0);
    }

    #pragma unroll
    for (int t = 0; t < 8; ++t) {
        const int k0 = (w * 8 + t) * 16;
        #pragma unroll
        for (int rr = 0; rr < 4; ++rr)
            scb[g * 4 + rr][k0 + arow] = f2bf(acc[t][rr]);
    }
    __syncthreads();

    // --- softmax with fused relsc + mask add (PB-Relax == plain softmax) ---
    for (int r = 0; r < 4; ++r) {
        const int row = w * 4 + r;
        const short* rp = relsc + (((size_t)(b * S_ + s0 + row)) * NH + n) * S_;
        float vals[8];
        float m = -1e30f;
        #pragma unroll
        for (int i = 0; i < 8; ++i) {
            vals[i] = bf2f(scb[row][l + 64 * i]) + bf2f(rp[l + 64 * i]) + mask[b * S_ + l + 64 * i];
            m = fmaxf(m, vals[i]);
        }
        #pragma unroll
        for (int off = 32; off >= 1; off >>= 1) m = fmaxf(m, __shfl_xor(m, off));
        float sum = 0.f;
        #pragma unroll
        for (int i = 0; i < 8; ++i) { vals[i] = __expf(vals[i] - m); sum += vals[i]; }
        #pragma unroll
        for (int off = 32; off >= 1; off >>= 1) sum += __shfl_xor(sum, off);
        const float inv = 1.0f / sum;
        #pragma unroll
        for (int i = 0; i < 8; ++i) pbf[row][l + 64 * i] = f2bf(vals[i] * inv);
    }
    __syncthreads();

    // --- PV via MFMA: out[s][h] = sum_k P[s][k] V^T[h][k] ---
    f32x4 pacc = (f32x4){0.f, 0.f, 0.f, 0.f};
    const short* vrow = vbf + ((size_t)(b * NH + n) * HD + w * 16 + arow) * S_ + g * 8;
    #pragma unroll
    for (int kk = 0; kk < 16; ++kk) {
        short8 aP = *(const short8*)&pbf[arow][kk * 32 + g * 8];
        short8 bV = *(const short8*)(vrow + kk * 32);
        pacc = __builtin_amdgcn_mfma_f32_16x16x32_bf16(aP, bV, pacc, 0, 0, 0);
    }
    #pragma unroll
    for (int rr = 0; rr < 4; ++rr) {
        const int srow = g * 4 + rr;
        out[((size_t)(b * S_ + s0 + srow)) * D_ + n * HD + w * 16 + arow] = pacc[rr];
    }
}

extern "C" void kernel_launch(void* const* d_in, const int* in_sizes, int n_in,
                              void* d_out, int out_size, void* d_ws, size_t ws_size,
                              hipStream_t stream) {
    const float* hidden = (const float*)d_in[0];
    const float* mask   = (const float*)d_in[1];
    const float* rel1   = (const float*)d_in[2];
    const float* rel2   = (const float*)d_in[3];
    const float* rel3   = (const float*)d_in[4];
    const float* Wq     = (const float*)d_in[5];
    const float* bq     = (const float*)d_in[6];
    const float* Wk     = (const float*)d_in[7];
    const float* bk     = (const float*)d_in[8];
    const float* Wv     = (const float*)d_in[9];
    const float* bv     = (const float*)d_in[10];
    float* out = (float*)d_out;

    const size_t per = (size_t)B_ * NH * S_ * HD;        // 786432
    short* qbf   = (short*)d_ws;                          // 1.5 MB
    short* kbf   = qbf + per;                             // 1.5 MB
    short* vbf   = kbf + per;                             // 1.5 MB (b,n,h,s)
    short* relsc = vbf + per;                             // 12.6 MB bf16 (b,s,n,k)

    qkv_gemm<<<dim3(16, 12, 3), 256, 0, stream>>>(hidden, Wq, Wk, Wv, bq, bk, bv, qbf, kbf, vbf);
    score_rel<<<dim3(8, S_, B_), 256, 0, stream>>>(qbf, rel1, rel2, rel3, relsc);
    smqkpv<<<dim3(S_ / 16, NH, B_), 256, 0, stream>>>(qbf, kbf, relsc, mask, vbf, out);
}